// Round 1
// baseline (516.367 us; speedup 1.0000x reference)
//
#include <hip/hip_runtime.h>
#include <math.h>

// Problem constants
#define NT 3650
#define NG 2000
#define NYV 5
#define NCOL 10000      // NG*NYV flattened (g*5+v)
#define NYEARS 10
#define NDAY 365
#define TILE 16
#define NTILE 625       // NCOL/TILE
#define P 372           // padded LDS col stride in floats (>=368, mult of 4; 372%32=20 -> good banks)
#define STATS_N 6
#define STATS_FLOATS (2*NYEARS*NCOL*STATS_N)   // 1,200,000 floats
#define SE_BLOCKS (NYEARS*NTILE)               // 6250
#define K2_THREADS (NCOL*STATS_N)              // 60000
#define K2_BLOCKS ((K2_THREADS+255)/256)       // 235

__device__ __forceinline__ float wave_sum(float x) {
  #pragma unroll
  for (int o = 32; o > 0; o >>= 1) x += __shfl_xor(x, o, 64);
  return x;
}

// Kernel 1: per-(tensor,year,col) mean + 5 order stats via in-register wave bitonic sort;
// fused per-ny squared-error partial sums. One block = one (year, 16-col tile), both tensors.
__global__ __launch_bounds__(1024) void k_stats(const float* __restrict__ outp,
                                                const float* __restrict__ targ,
                                                float* __restrict__ stats,
                                                float* __restrict__ se_part)
{
  __shared__ __align__(16) float lds[2][TILE * P];
  __shared__ float seW[16][5];
  const int bx = blockIdx.x;              // 6250 = NYEARS * NTILE
  const int year = bx / NTILE;
  const int tile = bx - year * NTILE;
  const int tid = threadIdx.x;
  const int lane = tid & 63;
  const int wid = tid >> 6;

  // init +inf pads for rows [365, P)
  if (tid < 2 * TILE * (P - NDAY)) {
    int tz = tid / (TILE * (P - NDAY));
    int rem = tid - tz * (TILE * (P - NDAY));
    int c = rem / (P - NDAY);
    int r = NDAY + (rem - c * (P - NDAY));
    lds[tz][c * P + r] = __builtin_inff();
  }

  // coalesced load: thread t -> col = t%16, rows t/16 + 64*it
  const int col = tid & 15;
  const int rowb = tid >> 4;
  const int gcol = tile * TILE + col;
  float se = 0.f;
  const size_t ybase = (size_t)year * NDAY * NCOL;
  #pragma unroll
  for (int it = 0; it < 6; ++it) {
    int row = rowb + it * 64;
    if (row < NDAY) {
      size_t gi = ybase + (size_t)row * NCOL + gcol;
      float a = outp[gi];
      float b = targ[gi];
      lds[0][col * P + row] = a;
      lds[1][col * P + row] = b;
      float d = a - b;
      se = fmaf(d, d, se);
    }
  }

  // per-ny SE reduction (ny = gcol % 5, constant per thread)
  const int ny = gcol % 5;
  #pragma unroll
  for (int v = 0; v < 5; ++v) {
    float x = (ny == v) ? se : 0.f;
    x = wave_sum(x);
    if (lane == 0) seW[wid][v] = x;
  }
  __syncthreads();
  if (tid < 5) {
    float s = 0.f;
    #pragma unroll
    for (int w = 0; w < 16; ++w) s += seW[w][tid];
    se_part[bx * 5 + tid] = s;
  }

  // sort phase: wave `wid` sorts col=wid, both tensors (sequential)
  #pragma unroll 1
  for (int tz = 0; tz < 2; ++tz) {
    const float* base = &lds[tz][wid * P];
    float x[8];
    if (lane < 46) {
      float4 v0 = *(const float4*)(base + (lane << 3));
      float4 v1 = *(const float4*)(base + (lane << 3) + 4);
      x[0] = v0.x; x[1] = v0.y; x[2] = v0.z; x[3] = v0.w;
      x[4] = v1.x; x[5] = v1.y; x[6] = v1.z; x[7] = v1.w;
    } else {
      #pragma unroll
      for (int r = 0; r < 8; ++r) x[r] = __builtin_inff();
    }

    // mean over the 365 valid elems
    float s = 0.f;
    const int e0 = lane << 3;
    #pragma unroll
    for (int r = 0; r < 8; ++r) s += (e0 + r < NDAY) ? x[r] : 0.f;
    s = wave_sum(s);
    const float mean = s * (1.f / 365.f);

    // bitonic sort of 512 (logical index e = lane*8 + r), ascending
    #pragma unroll
    for (int k = 2; k <= 512; k <<= 1) {
      #pragma unroll
      for (int j = k >> 1; j > 0; j >>= 1) {
        if (j < 8) {
          // in-lane exchange between regs r and r|j
          #pragma unroll
          for (int r = 0; r < 8; ++r) {
            if ((r & j) == 0) {
              const int r2 = r | j;
              bool asc;
              if (k < 8)        asc = ((r & k) == 0);        // compile-time
              else if (k == 512) asc = true;                  // e&512 == 0 always
              else              asc = ((lane & (k >> 3)) == 0);
              float a = x[r], b = x[r2];
              float mn = fminf(a, b), mx = fmaxf(a, b);
              x[r]  = asc ? mn : mx;
              x[r2] = asc ? mx : mn;
            }
          }
        } else {
          // cross-lane exchange: partner lane = lane ^ (j>>3), same reg
          const int jl = j >> 3;
          const bool lower = ((lane & jl) == 0);
          const bool asc = (k == 512) ? true : ((lane & (k >> 3)) == 0);
          const bool keepmin = (lower == asc);
          #pragma unroll
          for (int r = 0; r < 8; ++r) {
            float p = __shfl_xor(x[r], jl, 64);
            float mn = fminf(x[r], p), mx = fmaxf(x[r], p);
            x[r] = keepmin ? mn : mx;
          }
        }
      }
    }

    // extract ranks {364,357,182,109,7}: rank R -> lane R>>3, reg R&7
    float q364 = __shfl(x[4], 45, 64);
    float q357 = __shfl(x[5], 44, 64);
    float q182 = __shfl(x[6], 22, 64);
    float q109 = __shfl(x[5], 13, 64);
    float q7   = __shfl(x[7], 0, 64);
    if (lane == 0) {
      size_t sb = ((size_t)(tz * NYEARS + year) * NCOL + (size_t)(tile * TILE + wid)) * STATS_N;
      stats[sb + 0] = mean;
      stats[sb + 1] = q364;
      stats[sb + 2] = q357;
      stats[sb + 3] = q182;
      stats[sb + 4] = q109;
      stats[sb + 5] = q7;
    }
  }
}

// Kernel 2: Theil-Sen median of 45 pairwise slopes over 10 years, per (col,stat),
// both tensors; accumulate (medT - medP)^2 per block.
__global__ __launch_bounds__(256) void k_trend(const float* __restrict__ stats,
                                               float* __restrict__ trend_part)
{
  const int tid = blockIdx.x * 256 + threadIdx.x;
  float contrib = 0.f;
  if (tid < K2_THREADS) {
    float med[2];
    #pragma unroll 1
    for (int tz = 0; tz < 2; ++tz) {
      float xv[10];
      #pragma unroll
      for (int y = 0; y < NYEARS; ++y)
        xv[y] = stats[(size_t)tz * (NYEARS * NCOL * STATS_N) + (size_t)y * (NCOL * STATS_N) + tid];
      float d[45];
      int c = 0;
      #pragma unroll
      for (int i = 0; i < 10; ++i) {
        #pragma unroll
        for (int j = i + 1; j < 10; ++j) {
          d[c] = (xv[j] - xv[i]) / (float)(j - i);
          ++c;
        }
      }
      // stable rank-count selection of sorted[22] (lower-middle of 45)
      float m = 0.f;
      #pragma unroll
      for (int i = 0; i < 45; ++i) {
        int rank = 0;
        #pragma unroll
        for (int j = 0; j < 45; ++j) {
          if (j != i) {
            bool lt = (d[j] < d[i]) || ((d[j] == d[i]) && (j < i));
            rank += lt ? 1 : 0;
          }
        }
        m = (rank == 22) ? d[i] : m;
      }
      med[tz] = m;
    }
    float dd = med[1] - med[0];
    contrib = dd * dd;
  }
  float s = wave_sum(contrib);
  __shared__ float red[4];
  if ((threadIdx.x & 63) == 0) red[threadIdx.x >> 6] = s;
  __syncthreads();
  if (threadIdx.x == 0) trend_part[blockIdx.x] = red[0] + red[1] + red[2] + red[3];
}

// Kernel 3: deterministic final combine (single block).
__global__ __launch_bounds__(256) void k_final(const float* __restrict__ se_part,
                                               const float* __restrict__ trend_part,
                                               float* __restrict__ out)
{
  const int tid = threadIdx.x;
  float acc[5] = {0.f, 0.f, 0.f, 0.f, 0.f};
  for (int i = tid; i < SE_BLOCKS; i += 256) {
    #pragma unroll
    for (int v = 0; v < 5; ++v) acc[v] += se_part[i * 5 + v];
  }
  float tr = 0.f;
  for (int i = tid; i < K2_BLOCKS; i += 256) tr += trend_part[i];

  __shared__ float red[6][4];
  #pragma unroll
  for (int q = 0; q < 6; ++q) {
    float s = wave_sum(q < 5 ? acc[q] : tr);
    if ((tid & 63) == 0) red[q][tid >> 6] = s;
  }
  __syncthreads();
  if (tid == 0) {
    float loss = 0.f;
    const float inv = 1.f / (float)((double)NT * (double)NG);
    #pragma unroll
    for (int q = 0; q < 5; ++q)
      loss += sqrtf((red[q][0] + red[q][1] + red[q][2] + red[q][3]) * inv);
    loss += (red[5][0] + red[5][1] + red[5][2] + red[5][3]) / (float)NG;
    out[0] = loss;
  }
}

extern "C" void kernel_launch(void* const* d_in, const int* in_sizes, int n_in,
                              void* d_out, int out_size, void* d_ws, size_t ws_size,
                              hipStream_t stream)
{
  const float* outp = (const float*)d_in[0];  // "output" [3650,2000,5] f32
  const float* targ = (const float*)d_in[1];  // "target" [3650,2000,5] f32
  float* out = (float*)d_out;                 // scalar f32 loss

  // ws layout (floats): stats[2*10*10000*6] | se_part[6250*5] | trend_part[235]
  float* stats = (float*)d_ws;
  float* se_part = stats + STATS_FLOATS;
  float* trend_part = se_part + SE_BLOCKS * 5;

  k_stats<<<SE_BLOCKS, 1024, 0, stream>>>(outp, targ, stats, se_part);
  k_trend<<<K2_BLOCKS, 256, 0, stream>>>(stats, trend_part);
  k_final<<<1, 256, 0, stream>>>(se_part, trend_part, out);
}

// Round 2
// 464.146 us; speedup vs baseline: 1.1125x; 1.1125x over previous
//
#include <hip/hip_runtime.h>
#include <math.h>

// Problem constants
#define NT 3650
#define NG 2000
#define NYV 5
#define NCOL 10000      // NG*NYV flattened (g*5+v)
#define NYEARS 10
#define NDAY 365
#define TILE 16
#define NTILE 625       // NCOL/TILE
#define P 372           // padded LDS col stride in floats
#define STATS_N 6
#define STATS_FLOATS (2*NYEARS*NCOL*STATS_N)   // 1,200,000 floats
#define SE_BLOCKS (NYEARS*NTILE)               // 6250
#define K2_THREADS (NCOL*STATS_N)              // 60000
#define K2_BLOCKS ((K2_THREADS+255)/256)       // 235

__device__ __forceinline__ float wave_sum(float x) {
  #pragma unroll
  for (int o = 32; o > 0; o >>= 1) x += __shfl_xor(x, o, 64);
  return x;
}

// ---- sort building blocks (normalized bitonic: ALL compare-exchanges min->lower index) ----

#define CASR(a,b) { float _mn = fminf(a,b); b = fmaxf(a,b); a = _mn; }

// DPP lane-xor shuffle (quad_perm): CTRL 0xB1=xor1, 0x4E=xor2, 0x1B=xor3
template<int CTRL>
__device__ __forceinline__ float fdpp(float v) {
  int i = __builtin_bit_cast(int, v);
  int o = __builtin_amdgcn_update_dpp(i, i, CTRL, 0xF, 0xF, true);
  return __builtin_bit_cast(float, o);
}

// cross-lane pass via DS shuffle (ds_swizzle/bpermute). M = lane xor mask.
// REV: reversal pass, partner register = 7-r. lower: keep min (else max).
template<int M, bool REV>
__device__ __forceinline__ void cpass_ds(float x[8], float y[8], bool lower) {
  float px[8], py[8];
  #pragma unroll
  for (int r = 0; r < 8; ++r) {
    const int s = REV ? (7 - r) : r;
    px[r] = __shfl_xor(x[s], M, 64);
    py[r] = __shfl_xor(y[s], M, 64);
  }
  if (lower) {
    #pragma unroll
    for (int r = 0; r < 8; ++r) { x[r] = fminf(x[r], px[r]); y[r] = fminf(y[r], py[r]); }
  } else {
    #pragma unroll
    for (int r = 0; r < 8; ++r) { x[r] = fmaxf(x[r], px[r]); y[r] = fmaxf(y[r], py[r]); }
  }
}

// cross-lane pass via DPP (VALU pipe)
template<int CTRL, bool REV>
__device__ __forceinline__ void cpass_dpp(float x[8], float y[8], bool lower) {
  float px[8], py[8];
  #pragma unroll
  for (int r = 0; r < 8; ++r) {
    const int s = REV ? (7 - r) : r;
    px[r] = fdpp<CTRL>(x[s]);
    py[r] = fdpp<CTRL>(y[s]);
  }
  if (lower) {
    #pragma unroll
    for (int r = 0; r < 8; ++r) { x[r] = fminf(x[r], px[r]); y[r] = fminf(y[r], py[r]); }
  } else {
    #pragma unroll
    for (int r = 0; r < 8; ++r) { x[r] = fmaxf(x[r], px[r]); y[r] = fmaxf(y[r], py[r]); }
  }
}

// in-lane passes (compile-time pairs, min->lower)
__device__ __forceinline__ void il_rev_k2(float x[8]) { CASR(x[0],x[1]); CASR(x[2],x[3]); CASR(x[4],x[5]); CASR(x[6],x[7]); }
__device__ __forceinline__ void il_rev_k4(float x[8]) { CASR(x[0],x[3]); CASR(x[1],x[2]); CASR(x[4],x[7]); CASR(x[5],x[6]); }
__device__ __forceinline__ void il_rev_k8(float x[8]) { CASR(x[0],x[7]); CASR(x[1],x[6]); CASR(x[2],x[5]); CASR(x[3],x[4]); }
__device__ __forceinline__ void il_x1(float x[8])     { CASR(x[0],x[1]); CASR(x[2],x[3]); CASR(x[4],x[5]); CASR(x[6],x[7]); }
__device__ __forceinline__ void il_x2(float x[8])     { CASR(x[0],x[2]); CASR(x[1],x[3]); CASR(x[4],x[6]); CASR(x[5],x[7]); }
__device__ __forceinline__ void il_x4(float x[8])     { CASR(x[0],x[4]); CASR(x[1],x[5]); CASR(x[2],x[6]); CASR(x[3],x[7]); }
__device__ __forceinline__ void il_421(float x[8], float y[8]) {
  il_x4(x); il_x2(x); il_x1(x);
  il_x4(y); il_x2(y); il_x1(y);
}

// Kernel 1: per-(tensor,year,col) mean + 5 order stats; fused SE partials.
// One block = one (year, 16-col tile); wave w sorts col w for BOTH tensors simultaneously.
__global__ __launch_bounds__(1024) void k_stats(const float* __restrict__ outp,
                                                const float* __restrict__ targ,
                                                float* __restrict__ stats,
                                                float* __restrict__ se_part)
{
  __shared__ __align__(16) float lds[2][TILE * P];
  __shared__ float seW[16][5];
  const int bx = blockIdx.x;              // 6250 = NYEARS * NTILE
  const int year = bx / NTILE;
  const int tile = bx - year * NTILE;
  const int tid = threadIdx.x;
  const int lane = tid & 63;
  const int wid = tid >> 6;

  // init +inf pads for rows [365, P)
  if (tid < 2 * TILE * (P - NDAY)) {
    int tz = tid / (TILE * (P - NDAY));
    int rem = tid - tz * (TILE * (P - NDAY));
    int c = rem / (P - NDAY);
    int r = NDAY + (rem - c * (P - NDAY));
    lds[tz][c * P + r] = __builtin_inff();
  }

  // coalesced load: thread t -> col = t%16, rows t/16 + 64*it
  const int col = tid & 15;
  const int rowb = tid >> 4;
  const int gcolL = tile * TILE + col;
  float se = 0.f;
  const size_t ybase = (size_t)year * NDAY * NCOL;
  #pragma unroll
  for (int it = 0; it < 6; ++it) {
    int row = rowb + it * 64;
    if (row < NDAY) {
      size_t gi = ybase + (size_t)row * NCOL + gcolL;
      float a = outp[gi];
      float b = targ[gi];
      lds[0][col * P + row] = a;
      lds[1][col * P + row] = b;
      float d = a - b;
      se = fmaf(d, d, se);
    }
  }

  // per-ny SE reduction (ny = gcolL % 5, constant per thread)
  const int ny = gcolL % 5;
  #pragma unroll
  for (int v = 0; v < 5; ++v) {
    float sv = (ny == v) ? se : 0.f;
    sv = wave_sum(sv);
    if (lane == 0) seW[wid][v] = sv;
  }
  __syncthreads();
  if (tid < 5) {
    float s = 0.f;
    #pragma unroll
    for (int w = 0; w < 16; ++w) s += seW[w][tid];
    se_part[bx * 5 + tid] = s;
  }

  // ---- sort phase: wave wid sorts col=wid, x = output, y = target, merged ----
  float x[8], y[8];
  {
    const float* bx0 = &lds[0][wid * P];
    const float* bx1 = &lds[1][wid * P];
    if (lane < 46) {
      float4 a0 = *(const float4*)(bx0 + (lane << 3));
      float4 a1 = *(const float4*)(bx0 + (lane << 3) + 4);
      x[0]=a0.x; x[1]=a0.y; x[2]=a0.z; x[3]=a0.w; x[4]=a1.x; x[5]=a1.y; x[6]=a1.z; x[7]=a1.w;
      float4 b0 = *(const float4*)(bx1 + (lane << 3));
      float4 b1 = *(const float4*)(bx1 + (lane << 3) + 4);
      y[0]=b0.x; y[1]=b0.y; y[2]=b0.z; y[3]=b0.w; y[4]=b1.x; y[5]=b1.y; y[6]=b1.z; y[7]=b1.w;
    } else {
      #pragma unroll
      for (int r = 0; r < 8; ++r) { x[r] = __builtin_inff(); y[r] = __builtin_inff(); }
    }
  }

  // means over the 365 valid elems (pads are +inf, mask them)
  float sx = 0.f, sy = 0.f;
  {
    const int e0 = lane << 3;
    #pragma unroll
    for (int r = 0; r < 8; ++r) {
      bool valid = (e0 + r) < NDAY;
      sx += valid ? x[r] : 0.f;
      sy += valid ? y[r] : 0.f;
    }
  }
  sx = wave_sum(sx) * (1.f / 365.f);
  sy = wave_sum(sy) * (1.f / 365.f);

  // lane-role booleans (lower = keep min)
  const bool b1  = (lane & 1)  == 0;
  const bool b2  = (lane & 2)  == 0;
  const bool b4  = (lane & 4)  == 0;
  const bool b8  = (lane & 8)  == 0;
  const bool b16 = (lane & 16) == 0;
  const bool b32 = (lane & 32) == 0;

  // ---- normalized bitonic sort of 512 (e = lane*8 + r), ascending ----
  // k=2
  il_rev_k2(x); il_rev_k2(y);
  // k=4
  il_rev_k4(x); il_rev_k4(y); il_x1(x); il_x1(y);
  // k=8
  il_rev_k8(x); il_rev_k8(y); il_x2(x); il_x2(y); il_x1(x); il_x1(y);
  // k=16: rev e^15 (lane^1, reg 7-r), lower = b1
  cpass_dpp<0xB1, true>(x, y, b1);
  il_421(x, y);
  // k=32: rev e^31 (lane^3), b2; xor j=8 (lane^1), b1
  cpass_dpp<0x1B, true>(x, y, b2);
  cpass_dpp<0xB1, false>(x, y, b1);
  il_421(x, y);
  // k=64: rev e^63 (lane^7), b4; j=16 (lane^2), b2; j=8 (lane^1), b1
  cpass_ds<7, true>(x, y, b4);
  cpass_dpp<0x4E, false>(x, y, b2);
  cpass_dpp<0xB1, false>(x, y, b1);
  il_421(x, y);
  // k=128: rev lane^15, b8; j=32 lane^4, b4; j=16 dpp, b2; j=8 dpp, b1
  cpass_ds<15, true>(x, y, b8);
  cpass_ds<4, false>(x, y, b4);
  cpass_dpp<0x4E, false>(x, y, b2);
  cpass_dpp<0xB1, false>(x, y, b1);
  il_421(x, y);
  // k=256: rev lane^31, b16; j=64 lane^8, b8; j=32 lane^4, b4; dpp b2; dpp b1
  cpass_ds<31, true>(x, y, b16);
  cpass_ds<8, false>(x, y, b8);
  cpass_ds<4, false>(x, y, b4);
  cpass_dpp<0x4E, false>(x, y, b2);
  cpass_dpp<0xB1, false>(x, y, b1);
  il_421(x, y);
  // k=512: rev lane^63, b32; j=128 lane^16, b16; j=64 lane^8, b8; j=32 lane^4, b4; dpp b2; dpp b1
  cpass_ds<63, true>(x, y, b32);
  cpass_ds<16, false>(x, y, b16);
  cpass_ds<8, false>(x, y, b8);
  cpass_ds<4, false>(x, y, b4);
  cpass_dpp<0x4E, false>(x, y, b2);
  cpass_dpp<0xB1, false>(x, y, b1);
  il_421(x, y);

  // ---- extract ranks {364,357,182,109,7}: rank R -> lane R>>3, reg R&7 ----
  const int gc = tile * TILE + wid;
  const size_t sb0 = ((size_t)(0 * NYEARS + year) * NCOL + gc) * STATS_N;
  const size_t sb1 = ((size_t)(1 * NYEARS + year) * NCOL + gc) * STATS_N;
  if (lane == 0) {
    stats[sb0 + 0] = sx;   stats[sb1 + 0] = sy;       // means (broadcast by wave_sum)
    stats[sb0 + 5] = x[7]; stats[sb1 + 5] = y[7];     // rank 7
  } else if (lane == 13) {
    stats[sb0 + 4] = x[5]; stats[sb1 + 4] = y[5];     // rank 109
  } else if (lane == 22) {
    stats[sb0 + 3] = x[6]; stats[sb1 + 3] = y[6];     // rank 182
  } else if (lane == 44) {
    stats[sb0 + 2] = x[5]; stats[sb1 + 2] = y[5];     // rank 357
  } else if (lane == 45) {
    stats[sb0 + 1] = x[4]; stats[sb1 + 1] = y[4];     // rank 364
  }
}

// Kernel 2: Theil-Sen median of 45 pairwise slopes over 10 years, per (col,stat),
// both tensors; accumulate (medT - medP)^2 per block.
__global__ __launch_bounds__(256) void k_trend(const float* __restrict__ stats,
                                               float* __restrict__ trend_part)
{
  const int tid = blockIdx.x * 256 + threadIdx.x;
  float contrib = 0.f;
  if (tid < K2_THREADS) {
    float med[2];
    #pragma unroll 1
    for (int tz = 0; tz < 2; ++tz) {
      float xv[10];
      #pragma unroll
      for (int y = 0; y < NYEARS; ++y)
        xv[y] = stats[(size_t)tz * (NYEARS * NCOL * STATS_N) + (size_t)y * (NCOL * STATS_N) + tid];
      float d[45];
      int c = 0;
      #pragma unroll
      for (int i = 0; i < 10; ++i) {
        #pragma unroll
        for (int j = i + 1; j < 10; ++j) {
          d[c] = (xv[j] - xv[i]) / (float)(j - i);
          ++c;
        }
      }
      // stable rank-count selection of sorted[22] (lower-middle of 45)
      float m = 0.f;
      #pragma unroll
      for (int i = 0; i < 45; ++i) {
        int rank = 0;
        #pragma unroll
        for (int j = 0; j < 45; ++j) {
          if (j != i) {
            bool lt = (d[j] < d[i]) || ((d[j] == d[i]) && (j < i));
            rank += lt ? 1 : 0;
          }
        }
        m = (rank == 22) ? d[i] : m;
      }
      med[tz] = m;
    }
    float dd = med[1] - med[0];
    contrib = dd * dd;
  }
  float s = wave_sum(contrib);
  __shared__ float red[4];
  if ((threadIdx.x & 63) == 0) red[threadIdx.x >> 6] = s;
  __syncthreads();
  if (threadIdx.x == 0) trend_part[blockIdx.x] = red[0] + red[1] + red[2] + red[3];
}

// Kernel 3: deterministic final combine (single block).
__global__ __launch_bounds__(256) void k_final(const float* __restrict__ se_part,
                                               const float* __restrict__ trend_part,
                                               float* __restrict__ out)
{
  const int tid = threadIdx.x;
  float acc[5] = {0.f, 0.f, 0.f, 0.f, 0.f};
  for (int i = tid; i < SE_BLOCKS; i += 256) {
    #pragma unroll
    for (int v = 0; v < 5; ++v) acc[v] += se_part[i * 5 + v];
  }
  float tr = 0.f;
  for (int i = tid; i < K2_BLOCKS; i += 256) tr += trend_part[i];

  __shared__ float red[6][4];
  #pragma unroll
  for (int q = 0; q < 6; ++q) {
    float s = wave_sum(q < 5 ? acc[q] : tr);
    if ((tid & 63) == 0) red[q][tid >> 6] = s;
  }
  __syncthreads();
  if (tid == 0) {
    float loss = 0.f;
    const float inv = 1.f / (float)((double)NT * (double)NG);
    #pragma unroll
    for (int q = 0; q < 5; ++q)
      loss += sqrtf((red[q][0] + red[q][1] + red[q][2] + red[q][3]) * inv);
    loss += (red[5][0] + red[5][1] + red[5][2] + red[5][3]) / (float)NG;
    out[0] = loss;
  }
}

extern "C" void kernel_launch(void* const* d_in, const int* in_sizes, int n_in,
                              void* d_out, int out_size, void* d_ws, size_t ws_size,
                              hipStream_t stream)
{
  const float* outp = (const float*)d_in[0];  // "output" [3650,2000,5] f32
  const float* targ = (const float*)d_in[1];  // "target" [3650,2000,5] f32
  float* out = (float*)d_out;                 // scalar f32 loss

  // ws layout (floats): stats[2*10*10000*6] | se_part[6250*5] | trend_part[235]
  float* stats = (float*)d_ws;
  float* se_part = stats + STATS_FLOATS;
  float* trend_part = se_part + SE_BLOCKS * 5;

  k_stats<<<SE_BLOCKS, 1024, 0, stream>>>(outp, targ, stats, se_part);
  k_trend<<<K2_BLOCKS, 256, 0, stream>>>(stats, trend_part);
  k_final<<<1, 256, 0, stream>>>(se_part, trend_part, out);
}

// Round 3
// 446.482 us; speedup vs baseline: 1.1565x; 1.0396x over previous
//
#include <hip/hip_runtime.h>
#include <math.h>

// Problem constants
#define NT 3650
#define NG 2000
#define NYV 5
#define NCOL 10000      // NG*NYV flattened (g*5+v)
#define NYEARS 10
#define NDAY 365
#define TILE 16
#define NTILE 625       // NCOL/TILE
#define P 372           // padded LDS col stride in floats
#define STATS_N 6
#define STATS_FLOATS (2*NYEARS*NCOL*STATS_N)   // 1,200,000 floats
#define SE_BLOCKS (NYEARS*NTILE)               // 6250
#define K2_THREADS (NCOL*STATS_N)              // 60000
#define K2_BLOCKS ((K2_THREADS+255)/256)       // 235

// ---- cross-lane primitives (no per-call address VALU) ----

template<int IMM>
__device__ __forceinline__ float swzf(float v) {
  return __builtin_bit_cast(float, __builtin_amdgcn_ds_swizzle(__builtin_bit_cast(int, v), IMM));
}
__device__ __forceinline__ float bpermf(int addr, float v) {
  return __builtin_bit_cast(float, __builtin_amdgcn_ds_bpermute(addr, __builtin_bit_cast(int, v)));
}
template<int CTRL>
__device__ __forceinline__ float fdpp(float v) {
  int i = __builtin_bit_cast(int, v);
  int o = __builtin_amdgcn_update_dpp(i, i, CTRL, 0xF, 0xF, true);
  return __builtin_bit_cast(float, o);
}

// full-wave sum, result in all lanes; a32 = ((lane^32)<<2) precomputed
__device__ __forceinline__ float wsum64(float x, int a32) {
  x += swzf<0x041F>(x);   // xor 1
  x += swzf<0x081F>(x);   // xor 2
  x += swzf<0x101F>(x);   // xor 4
  x += swzf<0x201F>(x);   // xor 8
  x += swzf<0x401F>(x);   // xor 16
  x += bpermf(a32, x);    // xor 32
  return x;
}

// ---- sort building blocks (normalized bitonic: ALL CAS keep min at lower index) ----

#define CASR(a,b) { float _mn = fminf(a,b); b = fmaxf(a,b); a = _mn; }

// keep min (lower lanes) / max (upper lanes); shuffles already done under full exec
__device__ __forceinline__ void sel8(float x[8], float y[8],
                                     const float px[8], const float py[8], bool lower) {
  if (lower) {
    #pragma unroll
    for (int r = 0; r < 8; ++r) { x[r] = fminf(x[r], px[r]); y[r] = fminf(y[r], py[r]); }
  } else {
    #pragma unroll
    for (int r = 0; r < 8; ++r) { x[r] = fmaxf(x[r], px[r]); y[r] = fmaxf(y[r], py[r]); }
  }
}

template<int IMM, bool REV>
__device__ __forceinline__ void cpass_swz(float x[8], float y[8], bool lower) {
  float px[8], py[8];
  #pragma unroll
  for (int r = 0; r < 8; ++r) {
    const int s = REV ? (7 - r) : r;
    px[r] = swzf<IMM>(x[s]);
    py[r] = swzf<IMM>(y[s]);
  }
  sel8(x, y, px, py, lower);
}

template<int CTRL, bool REV>
__device__ __forceinline__ void cpass_dpp(float x[8], float y[8], bool lower) {
  float px[8], py[8];
  #pragma unroll
  for (int r = 0; r < 8; ++r) {
    const int s = REV ? (7 - r) : r;
    px[r] = fdpp<CTRL>(x[s]);
    py[r] = fdpp<CTRL>(y[s]);
  }
  sel8(x, y, px, py, lower);
}

// mask-63 reversal via bpermute with precomputed address
__device__ __forceinline__ void cpass_bp63(float x[8], float y[8], int a63, bool lower) {
  float px[8], py[8];
  #pragma unroll
  for (int r = 0; r < 8; ++r) {
    const int s = 7 - r;
    px[r] = bpermf(a63, x[s]);
    py[r] = bpermf(a63, y[s]);
  }
  sel8(x, y, px, py, lower);
}

// in-lane passes
__device__ __forceinline__ void il_rev_k2(float x[8]) { CASR(x[0],x[1]); CASR(x[2],x[3]); CASR(x[4],x[5]); CASR(x[6],x[7]); }
__device__ __forceinline__ void il_rev_k4(float x[8]) { CASR(x[0],x[3]); CASR(x[1],x[2]); CASR(x[4],x[7]); CASR(x[5],x[6]); }
__device__ __forceinline__ void il_rev_k8(float x[8]) { CASR(x[0],x[7]); CASR(x[1],x[6]); CASR(x[2],x[5]); CASR(x[3],x[4]); }
__device__ __forceinline__ void il_x1(float x[8])     { CASR(x[0],x[1]); CASR(x[2],x[3]); CASR(x[4],x[5]); CASR(x[6],x[7]); }
__device__ __forceinline__ void il_x2(float x[8])     { CASR(x[0],x[2]); CASR(x[1],x[3]); CASR(x[4],x[6]); CASR(x[5],x[7]); }
__device__ __forceinline__ void il_x4(float x[8])     { CASR(x[0],x[4]); CASR(x[1],x[5]); CASR(x[2],x[6]); CASR(x[3],x[7]); }
__device__ __forceinline__ void il_421(float x[8], float y[8]) {
  il_x4(x); il_x2(x); il_x1(x);
  il_x4(y); il_x2(y); il_x1(y);
}

// Kernel 1: per-(tensor,year,col) mean + 5 order stats; fused SE partials.
__global__ __launch_bounds__(1024, 8) void k_stats(const float* __restrict__ outp,
                                                   const float* __restrict__ targ,
                                                   float* __restrict__ stats,
                                                   float* __restrict__ se_part)
{
  __shared__ __align__(16) float lds[2][TILE * P];
  __shared__ float seW[16][5];
  const int bx = blockIdx.x;              // 6250 = NYEARS * NTILE
  const int year = bx / NTILE;
  const int tile = bx - year * NTILE;
  const int tid = threadIdx.x;
  const int lane = tid & 63;
  const int wid = tid >> 6;
  const int a32 = ((lane ^ 32) << 2);
  const int a63 = ((lane ^ 63) << 2);

  // init +inf pads for rows [365, P)
  if (tid < 2 * TILE * (P - NDAY)) {
    int tz = tid / (TILE * (P - NDAY));
    int rem = tid - tz * (TILE * (P - NDAY));
    int c = rem / (P - NDAY);
    int r = NDAY + (rem - c * (P - NDAY));
    lds[tz][c * P + r] = __builtin_inff();
  }

  // coalesced load: thread t -> col = t%16, rows t/16 + 64*it
  const int col = tid & 15;
  const int rowb = tid >> 4;
  const int gcolL = tile * TILE + col;
  float se = 0.f;
  const size_t ybase = (size_t)year * NDAY * NCOL;
  #pragma unroll
  for (int it = 0; it < 6; ++it) {
    int row = rowb + it * 64;
    if (row < NDAY) {
      size_t gi = ybase + (size_t)row * NCOL + gcolL;
      float a = outp[gi];
      float b = targ[gi];
      lds[0][col * P + row] = a;
      lds[1][col * P + row] = b;
      float d = a - b;
      se = fmaf(d, d, se);
    }
  }

  // SE reduction: first over the 4 row-groups (lanes l, l^16, l^32, l^48 share a col)
  se += swzf<0x401F>(se);
  se += bpermf(a32, se);
  // then 16 cols -> 5 ny bins within the 16-lane group (masks 1,2,4,8)
  const int nyl = (tile * TILE + (lane & 15)) % 5;
  float sv[5];
  #pragma unroll
  for (int v = 0; v < 5; ++v) {
    float t = (nyl == v) ? se : 0.f;
    t += swzf<0x041F>(t);
    t += swzf<0x081F>(t);
    t += swzf<0x101F>(t);
    t += swzf<0x201F>(t);
    sv[v] = t;
  }
  if (lane == 0) {
    #pragma unroll
    for (int v = 0; v < 5; ++v) seW[wid][v] = sv[v];
  }
  __syncthreads();
  if (tid < 5) {
    float s = 0.f;
    #pragma unroll
    for (int w = 0; w < 16; ++w) s += seW[w][tid];
    se_part[bx * 5 + tid] = s;
  }

  // ---- sort phase: wave wid sorts col=wid, x = output, y = target, merged ----
  float x[8], y[8];
  {
    const float* bx0 = &lds[0][wid * P];
    const float* bx1 = &lds[1][wid * P];
    if (lane < 46) {
      float4 a0 = *(const float4*)(bx0 + (lane << 3));
      float4 a1 = *(const float4*)(bx0 + (lane << 3) + 4);
      x[0]=a0.x; x[1]=a0.y; x[2]=a0.z; x[3]=a0.w; x[4]=a1.x; x[5]=a1.y; x[6]=a1.z; x[7]=a1.w;
      float4 b0 = *(const float4*)(bx1 + (lane << 3));
      float4 b1 = *(const float4*)(bx1 + (lane << 3) + 4);
      y[0]=b0.x; y[1]=b0.y; y[2]=b0.z; y[3]=b0.w; y[4]=b1.x; y[5]=b1.y; y[6]=b1.z; y[7]=b1.w;
    } else {
      #pragma unroll
      for (int r = 0; r < 8; ++r) { x[r] = __builtin_inff(); y[r] = __builtin_inff(); }
    }
  }

  // means over the 365 valid elems (pads are +inf, mask them)
  float sx = 0.f, sy = 0.f;
  {
    const int e0 = lane << 3;
    #pragma unroll
    for (int r = 0; r < 8; ++r) {
      bool valid = (e0 + r) < NDAY;
      sx += valid ? x[r] : 0.f;
      sy += valid ? y[r] : 0.f;
    }
  }
  sx = wsum64(sx, a32) * (1.f / 365.f);
  sy = wsum64(sy, a32) * (1.f / 365.f);

  // lane-role booleans (lower = keep min)
  const bool b1  = (lane & 1)  == 0;
  const bool b2  = (lane & 2)  == 0;
  const bool b4  = (lane & 4)  == 0;
  const bool b8  = (lane & 8)  == 0;
  const bool b16 = (lane & 16) == 0;
  const bool b32 = (lane & 32) == 0;

  // ---- normalized bitonic sort of 512 (e = lane*8 + r), ascending ----
  // k=2
  il_rev_k2(x); il_rev_k2(y);
  // k=4
  il_rev_k4(x); il_rev_k4(y); il_x1(x); il_x1(y);
  // k=8
  il_rev_k8(x); il_rev_k8(y); il_x2(x); il_x2(y); il_x1(x); il_x1(y);
  // k=16: rev lane^1 (reg-rev)
  cpass_dpp<0xB1, true>(x, y, b1);
  il_421(x, y);
  // k=32: rev lane^3; j8 lane^1
  cpass_dpp<0x1B, true>(x, y, b2);
  cpass_dpp<0xB1, false>(x, y, b1);
  il_421(x, y);
  // k=64: rev lane^7 (ROW_HALF_MIRROR); j16 lane^2; j8 lane^1
  cpass_dpp<0x141, true>(x, y, b4);
  cpass_dpp<0x4E, false>(x, y, b2);
  cpass_dpp<0xB1, false>(x, y, b1);
  il_421(x, y);
  // k=128: rev lane^15 (ROW_MIRROR); j32 lane^4 swz; j16; j8
  cpass_dpp<0x140, true>(x, y, b8);
  cpass_swz<0x101F, false>(x, y, b4);
  cpass_dpp<0x4E, false>(x, y, b2);
  cpass_dpp<0xB1, false>(x, y, b1);
  il_421(x, y);
  // k=256: rev lane^31 swz; j64 lane^8 swz; j32 lane^4 swz; j16; j8
  cpass_swz<0x7C1F, true>(x, y, b16);
  cpass_swz<0x201F, false>(x, y, b8);
  cpass_swz<0x101F, false>(x, y, b4);
  cpass_dpp<0x4E, false>(x, y, b2);
  cpass_dpp<0xB1, false>(x, y, b1);
  il_421(x, y);
  // k=512: rev lane^63 bperm; j128 lane^16 swz; j64 lane^8; j32 lane^4; j16; j8
  cpass_bp63(x, y, a63, b32);
  cpass_swz<0x401F, false>(x, y, b16);
  cpass_swz<0x201F, false>(x, y, b8);
  cpass_swz<0x101F, false>(x, y, b4);
  cpass_dpp<0x4E, false>(x, y, b2);
  cpass_dpp<0xB1, false>(x, y, b1);
  il_421(x, y);

  // ---- extract ranks {364,357,182,109,7}: rank R -> lane R>>3, reg R&7 ----
  const int gc = tile * TILE + wid;
  const size_t sb0 = ((size_t)(0 * NYEARS + year) * NCOL + gc) * STATS_N;
  const size_t sb1 = ((size_t)(1 * NYEARS + year) * NCOL + gc) * STATS_N;
  if (lane == 0) {
    stats[sb0 + 0] = sx;   stats[sb1 + 0] = sy;       // means (broadcast by wsum64)
    stats[sb0 + 5] = x[7]; stats[sb1 + 5] = y[7];     // rank 7
  } else if (lane == 13) {
    stats[sb0 + 4] = x[5]; stats[sb1 + 4] = y[5];     // rank 109
  } else if (lane == 22) {
    stats[sb0 + 3] = x[6]; stats[sb1 + 3] = y[6];     // rank 182
  } else if (lane == 44) {
    stats[sb0 + 2] = x[5]; stats[sb1 + 2] = y[5];     // rank 357
  } else if (lane == 45) {
    stats[sb0 + 1] = x[4]; stats[sb1 + 1] = y[4];     // rank 364
  }
}

// Kernel 2: Theil-Sen median of 45 pairwise slopes over 10 years, per (col,stat).
__global__ __launch_bounds__(256) void k_trend(const float* __restrict__ stats,
                                               float* __restrict__ trend_part)
{
  const int tid = blockIdx.x * 256 + threadIdx.x;
  const int a32 = (((threadIdx.x & 63) ^ 32) << 2);
  float contrib = 0.f;
  if (tid < K2_THREADS) {
    float med[2];
    #pragma unroll 1
    for (int tz = 0; tz < 2; ++tz) {
      float xv[10];
      #pragma unroll
      for (int y = 0; y < NYEARS; ++y)
        xv[y] = stats[(size_t)tz * (NYEARS * NCOL * STATS_N) + (size_t)y * (NCOL * STATS_N) + tid];
      float d[45];
      int c = 0;
      #pragma unroll
      for (int i = 0; i < 10; ++i) {
        #pragma unroll
        for (int j = i + 1; j < 10; ++j) {
          d[c] = (xv[j] - xv[i]) / (float)(j - i);
          ++c;
        }
      }
      // stable rank-count selection of sorted[22] (lower-middle of 45)
      float m = 0.f;
      #pragma unroll
      for (int i = 0; i < 45; ++i) {
        int rank = 0;
        #pragma unroll
        for (int j = 0; j < 45; ++j) {
          if (j != i) {
            bool lt = (d[j] < d[i]) || ((d[j] == d[i]) && (j < i));
            rank += lt ? 1 : 0;
          }
        }
        m = (rank == 22) ? d[i] : m;
      }
      med[tz] = m;
    }
    float dd = med[1] - med[0];
    contrib = dd * dd;
  }
  float s = wsum64(contrib, a32);
  __shared__ float red[4];
  if ((threadIdx.x & 63) == 0) red[threadIdx.x >> 6] = s;
  __syncthreads();
  if (threadIdx.x == 0) trend_part[blockIdx.x] = red[0] + red[1] + red[2] + red[3];
}

// Kernel 3: deterministic final combine (single block, 1024 threads).
__global__ __launch_bounds__(1024) void k_final(const float* __restrict__ se_part,
                                                const float* __restrict__ trend_part,
                                                float* __restrict__ out)
{
  const int tid = threadIdx.x;
  const int lane = tid & 63;
  const int wid = tid >> 6;
  const int a32 = ((lane ^ 32) << 2);
  float acc[5] = {0.f, 0.f, 0.f, 0.f, 0.f};
  for (int i = tid; i < SE_BLOCKS; i += 1024) {
    #pragma unroll
    for (int v = 0; v < 5; ++v) acc[v] += se_part[i * 5 + v];
  }
  float tr = 0.f;
  for (int i = tid; i < K2_BLOCKS; i += 1024) tr += trend_part[i];

  __shared__ float red[6][16];
  #pragma unroll
  for (int q = 0; q < 6; ++q) {
    float s = wsum64(q < 5 ? acc[q] : tr, a32);
    if (lane == 0) red[q][wid] = s;
  }
  __syncthreads();
  if (tid == 0) {
    float loss = 0.f;
    const float inv = 1.f / (float)((double)NT * (double)NG);
    #pragma unroll
    for (int q = 0; q < 5; ++q) {
      float s = 0.f;
      #pragma unroll
      for (int w = 0; w < 16; ++w) s += red[q][w];
      loss += sqrtf(s * inv);
    }
    float s5 = 0.f;
    #pragma unroll
    for (int w = 0; w < 16; ++w) s5 += red[5][w];
    loss += s5 / (float)NG;
    out[0] = loss;
  }
}

extern "C" void kernel_launch(void* const* d_in, const int* in_sizes, int n_in,
                              void* d_out, int out_size, void* d_ws, size_t ws_size,
                              hipStream_t stream)
{
  const float* outp = (const float*)d_in[0];  // "output" [3650,2000,5] f32
  const float* targ = (const float*)d_in[1];  // "target" [3650,2000,5] f32
  float* out = (float*)d_out;                 // scalar f32 loss

  // ws layout (floats): stats[2*10*10000*6] | se_part[6250*5] | trend_part[235]
  float* stats = (float*)d_ws;
  float* se_part = stats + STATS_FLOATS;
  float* trend_part = se_part + SE_BLOCKS * 5;

  k_stats<<<SE_BLOCKS, 1024, 0, stream>>>(outp, targ, stats, se_part);
  k_trend<<<K2_BLOCKS, 256, 0, stream>>>(stats, trend_part);
  k_final<<<1, 1024, 0, stream>>>(se_part, trend_part, out);
}

// Round 4
// 280.200 us; speedup vs baseline: 1.8429x; 1.5934x over previous
//
#include <hip/hip_runtime.h>
#include <math.h>

// Problem constants
#define NT 3650
#define NG 2000
#define NYV 5
#define NCOL 10000      // NG*NYV flattened (g*5+v)
#define NYEARS 10
#define NDAY 365
#define TILE 16
#define NTILE 625       // NCOL/TILE
#define P 372           // padded LDS col stride in floats (>= 366 needed for A|B rewrite)
#define STATS_N 6
#define STATS_FLOATS (2*NYEARS*NCOL*STATS_N)   // 1,200,000 floats
#define SE_BLOCKS (NYEARS*NTILE)               // 6250
#define K2_THREADS (NCOL*STATS_N)              // 60000
#define K2_BLOCKS ((K2_THREADS+255)/256)       // 235

// ---- cross-lane primitives (no per-call address VALU) ----

template<int IMM>
__device__ __forceinline__ float swzf(float v) {
  return __builtin_bit_cast(float, __builtin_amdgcn_ds_swizzle(__builtin_bit_cast(int, v), IMM));
}
template<int IMM>
__device__ __forceinline__ unsigned uswz(unsigned v) {
  return (unsigned)__builtin_amdgcn_ds_swizzle((int)v, IMM);
}
__device__ __forceinline__ float bpermf(int addr, float v) {
  return __builtin_bit_cast(float, __builtin_amdgcn_ds_bpermute(addr, __builtin_bit_cast(int, v)));
}
template<int CTRL>
__device__ __forceinline__ unsigned udpp(unsigned v) {
  return (unsigned)__builtin_amdgcn_update_dpp((int)v, (int)v, CTRL, 0xF, 0xF, true);
}

// full-wave float sum, result in all lanes; a32 = ((lane^32)<<2) precomputed
__device__ __forceinline__ float wsum64(float x, int a32) {
  x += swzf<0x041F>(x);   // xor 1
  x += swzf<0x081F>(x);   // xor 2
  x += swzf<0x101F>(x);   // xor 4
  x += swzf<0x201F>(x);   // xor 8
  x += swzf<0x401F>(x);   // xor 16
  x += bpermf(a32, x);    // xor 32
  return x;
}

// ---- sortable u32 key mapping (strictly monotone) ----
__device__ __forceinline__ unsigned mapkey(float f) {
  unsigned b = __builtin_bit_cast(unsigned, f);
  unsigned asr = (unsigned)(((int)b) >> 31);
  return b ^ (asr | 0x80000000u);
}
__device__ __forceinline__ float unmapkey(unsigned u) {
  unsigned asr = (unsigned)(((int)u) >> 31);
  unsigned m = (~asr) | 0x80000000u;
  return __builtin_bit_cast(float, u ^ m);
}

// ---- u32 sort building blocks (normalized bitonic: ALL CAS keep min at lower index) ----

__device__ __forceinline__ unsigned umn(unsigned a, unsigned b) { return a < b ? a : b; }
__device__ __forceinline__ unsigned umx(unsigned a, unsigned b) { return a > b ? a : b; }
#define CASU(a,b) { unsigned _mn = umn(a,b); b = umx(a,b); a = _mn; }

// branchless per-lane keep-min/keep-max select
__device__ __forceinline__ void usel(unsigned x[8], unsigned y[8],
                                     const unsigned px[8], const unsigned py[8], bool up) {
  #pragma unroll
  for (int r = 0; r < 8; ++r) {
    x[r] = ((px[r] < x[r]) != up) ? px[r] : x[r];
    y[r] = ((py[r] < y[r]) != up) ? py[r] : y[r];
  }
}

template<int IMM, bool REV>
__device__ __forceinline__ void ucpass_swz(unsigned x[8], unsigned y[8], bool up) {
  unsigned px[8], py[8];
  #pragma unroll
  for (int r = 0; r < 8; ++r) {
    const int s = REV ? (7 - r) : r;
    px[r] = uswz<IMM>(x[s]);
    py[r] = uswz<IMM>(y[s]);
  }
  usel(x, y, px, py, up);
}

template<int CTRL, bool REV>
__device__ __forceinline__ void ucpass_dpp(unsigned x[8], unsigned y[8], bool up) {
  unsigned px[8], py[8];
  #pragma unroll
  for (int r = 0; r < 8; ++r) {
    const int s = REV ? (7 - r) : r;
    px[r] = udpp<CTRL>(x[s]);
    py[r] = udpp<CTRL>(y[s]);
  }
  usel(x, y, px, py, up);
}

// in-lane passes
__device__ __forceinline__ void uil_rev_k2(unsigned x[8]) { CASU(x[0],x[1]); CASU(x[2],x[3]); CASU(x[4],x[5]); CASU(x[6],x[7]); }
__device__ __forceinline__ void uil_rev_k4(unsigned x[8]) { CASU(x[0],x[3]); CASU(x[1],x[2]); CASU(x[4],x[7]); CASU(x[5],x[6]); }
__device__ __forceinline__ void uil_rev_k8(unsigned x[8]) { CASU(x[0],x[7]); CASU(x[1],x[6]); CASU(x[2],x[5]); CASU(x[3],x[4]); }
__device__ __forceinline__ void uil_x1(unsigned x[8])     { CASU(x[0],x[1]); CASU(x[2],x[3]); CASU(x[4],x[5]); CASU(x[6],x[7]); }
__device__ __forceinline__ void uil_x2(unsigned x[8])     { CASU(x[0],x[2]); CASU(x[1],x[3]); CASU(x[4],x[6]); CASU(x[5],x[7]); }
__device__ __forceinline__ void uil_x4(unsigned x[8])     { CASU(x[0],x[4]); CASU(x[1],x[5]); CASU(x[2],x[6]); CASU(x[3],x[7]); }
__device__ __forceinline__ void uil_421(unsigned x[8], unsigned y[8]) {
  uil_x4(x); uil_x2(x); uil_x1(x);
  uil_x4(y); uil_x2(y); uil_x1(y);
}

// Kernel 1: per-(tensor,year,col) mean + 5 order stats; fused SE partials.
// One block = (year, 16-col tile); wave w handles col w, both tensors.
// Sort only to k=256 (two ascending runs A=days 0..255, B=days 256..364+pads),
// then merge-path binary search in LDS for the 5 exact ranks.
__global__ __launch_bounds__(1024, 8) void k_stats(const float* __restrict__ outp,
                                                   const float* __restrict__ targ,
                                                   float* __restrict__ stats,
                                                   float* __restrict__ se_part)
{
  __shared__ __align__(16) float lds[2][TILE * P];
  __shared__ float seW[16][5];
  const int bx = blockIdx.x;              // 6250 = NYEARS * NTILE
  const int year = bx / NTILE;
  const int tile = bx - year * NTILE;
  const int tid = threadIdx.x;
  const int lane = tid & 63;
  const int wid = tid >> 6;
  const int a32 = ((lane ^ 32) << 2);

  // init +inf pads for rows [365, P)
  if (tid < 2 * TILE * (P - NDAY)) {
    int tz = tid / (TILE * (P - NDAY));
    int rem = tid - tz * (TILE * (P - NDAY));
    int c = rem / (P - NDAY);
    int r = NDAY + (rem - c * (P - NDAY));
    lds[tz][c * P + r] = __builtin_inff();
  }

  // coalesced load: thread t -> col = t%16, rows t/16 + 64*it
  const int col = tid & 15;
  const int rowb = tid >> 4;
  const int gcolL = tile * TILE + col;
  float se = 0.f;
  const size_t ybase = (size_t)year * NDAY * NCOL;
  #pragma unroll
  for (int it = 0; it < 6; ++it) {
    int row = rowb + it * 64;
    if (row < NDAY) {
      size_t gi = ybase + (size_t)row * NCOL + gcolL;
      float a = outp[gi];
      float b = targ[gi];
      lds[0][col * P + row] = a;
      lds[1][col * P + row] = b;
      float d = a - b;
      se = fmaf(d, d, se);
    }
  }

  // SE reduction: over 4 row-groups (lanes l, l^16, l^32, l^48 share a col)
  se += swzf<0x401F>(se);
  se += bpermf(a32, se);
  // then 16 cols -> 5 ny bins within the 16-lane group
  const int nyl = (tile * TILE + (lane & 15)) % 5;
  float sv[5];
  #pragma unroll
  for (int v = 0; v < 5; ++v) {
    float t = (nyl == v) ? se : 0.f;
    t += swzf<0x041F>(t);
    t += swzf<0x081F>(t);
    t += swzf<0x101F>(t);
    t += swzf<0x201F>(t);
    sv[v] = t;
  }
  if (lane == 0) {
    #pragma unroll
    for (int v = 0; v < 5; ++v) seW[wid][v] = sv[v];
  }
  __syncthreads();
  if (tid < 5) {
    float s = 0.f;
    #pragma unroll
    for (int w = 0; w < 16; ++w) s += seW[w][tid];
    se_part[bx * 5 + tid] = s;
  }

  // ---- sort phase: wave wid, col=wid, x = output, y = target ----
  float fx[8], fy[8];
  {
    const float* bx0 = &lds[0][wid * P];
    const float* bx1 = &lds[1][wid * P];
    if (lane < 46) {
      float4 a0 = *(const float4*)(bx0 + (lane << 3));
      float4 a1 = *(const float4*)(bx0 + (lane << 3) + 4);
      fx[0]=a0.x; fx[1]=a0.y; fx[2]=a0.z; fx[3]=a0.w; fx[4]=a1.x; fx[5]=a1.y; fx[6]=a1.z; fx[7]=a1.w;
      float4 b0 = *(const float4*)(bx1 + (lane << 3));
      float4 b1 = *(const float4*)(bx1 + (lane << 3) + 4);
      fy[0]=b0.x; fy[1]=b0.y; fy[2]=b0.z; fy[3]=b0.w; fy[4]=b1.x; fy[5]=b1.y; fy[6]=b1.z; fy[7]=b1.w;
    } else {
      #pragma unroll
      for (int r = 0; r < 8; ++r) { fx[r] = __builtin_inff(); fy[r] = __builtin_inff(); }
    }
  }

  // means over the 365 valid elems (pads are +inf, mask them)
  float sx = 0.f, sy = 0.f;
  {
    const int e0 = lane << 3;
    #pragma unroll
    for (int r = 0; r < 8; ++r) {
      bool valid = (e0 + r) < NDAY;
      sx += valid ? fx[r] : 0.f;
      sy += valid ? fy[r] : 0.f;
    }
  }
  sx = wsum64(sx, a32) * (1.f / 365.f);
  sy = wsum64(sy, a32) * (1.f / 365.f);

  // map to sortable u32 keys
  unsigned x[8], y[8];
  #pragma unroll
  for (int r = 0; r < 8; ++r) { x[r] = mapkey(fx[r]); y[r] = mapkey(fy[r]); }

  // lane-role booleans (up = keep max)
  const bool u1  = (lane & 1)  != 0;
  const bool u2  = (lane & 2)  != 0;
  const bool u4  = (lane & 4)  != 0;
  const bool u8  = (lane & 8)  != 0;
  const bool u16 = (lane & 16) != 0;

  // ---- normalized bitonic to k=256 (e = lane*8 + r) ----
  // k=2..8 in-lane
  uil_rev_k2(x); uil_rev_k2(y);
  uil_rev_k4(x); uil_rev_k4(y); uil_x1(x); uil_x1(y);
  uil_rev_k8(x); uil_rev_k8(y); uil_x2(x); uil_x2(y); uil_x1(x); uil_x1(y);
  // k=16: rev lane^1 (reg-rev)
  ucpass_dpp<0xB1, true>(x, y, u1);
  uil_421(x, y);
  // k=32: rev lane^3; j8 lane^1
  ucpass_dpp<0x1B, true>(x, y, u2);
  ucpass_dpp<0xB1, false>(x, y, u1);
  uil_421(x, y);
  // k=64: rev lane^7 (ROW_HALF_MIRROR); j16 lane^2; j8 lane^1
  ucpass_dpp<0x141, true>(x, y, u4);
  ucpass_dpp<0x4E, false>(x, y, u2);
  ucpass_dpp<0xB1, false>(x, y, u1);
  uil_421(x, y);
  // k=128: rev lane^15 (ROW_MIRROR); j32 lane^4 swz; j16; j8
  ucpass_dpp<0x140, true>(x, y, u8);
  ucpass_swz<0x101F, false>(x, y, u4);
  ucpass_dpp<0x4E, false>(x, y, u2);
  ucpass_dpp<0xB1, false>(x, y, u1);
  uil_421(x, y);
  // k=256: rev lane^31 swz; j64 lane^8 swz; j32 lane^4 swz; j16; j8
  ucpass_swz<0x7C1F, true>(x, y, u16);
  ucpass_swz<0x201F, false>(x, y, u8);
  ucpass_swz<0x101F, false>(x, y, u4);
  ucpass_dpp<0x4E, false>(x, y, u2);
  ucpass_dpp<0xB1, false>(x, y, u1);
  uil_421(x, y);

  // Now lanes 0-31 hold ascending run A (days 0..255),
  // lanes 32-63 ascending run B (days 256..364 + inf pads).
  // Write A|B back into this wave's own staging region: slot = lane*8 + r  (<= 367 < 372)
  if (lane < 46) {
    float* w0 = &lds[0][wid * P + (lane << 3)];
    float* w1 = &lds[1][wid * P + (lane << 3)];
    float4 v0, v1;
    v0.x = __builtin_bit_cast(float, x[0]); v0.y = __builtin_bit_cast(float, x[1]);
    v0.z = __builtin_bit_cast(float, x[2]); v0.w = __builtin_bit_cast(float, x[3]);
    v1.x = __builtin_bit_cast(float, x[4]); v1.y = __builtin_bit_cast(float, x[5]);
    v1.z = __builtin_bit_cast(float, x[6]); v1.w = __builtin_bit_cast(float, x[7]);
    *(float4*)w0 = v0; *(float4*)(w0 + 4) = v1;
    v0.x = __builtin_bit_cast(float, y[0]); v0.y = __builtin_bit_cast(float, y[1]);
    v0.z = __builtin_bit_cast(float, y[2]); v0.w = __builtin_bit_cast(float, y[3]);
    v1.x = __builtin_bit_cast(float, y[4]); v1.y = __builtin_bit_cast(float, y[5]);
    v1.z = __builtin_bit_cast(float, y[6]); v1.w = __builtin_bit_cast(float, y[7]);
    *(float4*)w1 = v0; *(float4*)(w1 + 4) = v1;
  }
  // same-wave LDS produce->consume: prevent compiler reordering (HW DS pipe is in-order per wave)
  __asm__ __volatile__("" ::: "memory");

  // ---- merge-path selection of ranks {364,357,182,109,7} ----
  const int gc = tile * TILE + wid;
  const size_t sb0 = ((size_t)year * NCOL + gc) * STATS_N;
  const size_t sb1 = ((size_t)(NYEARS + year) * NCOL + gc) * STATS_N;
  if (lane < 10) {
    int q = lane, tz = 0;
    if (lane >= 5) { q = lane - 5; tz = 1; }
    // rank R per q: {364,357,182,109,7}; k1 = R+1
    int k1 = (q == 0) ? 365 : (q == 1) ? 358 : (q == 2) ? 183 : (q == 3) ? 110 : 8;
    const float* base = (tz == 0) ? &lds[0][wid * P] : &lds[1][wid * P];
    // A = base[0..255] (256 keys), B = base[256..364] (109 keys), both ascending u32
    int lo = k1 - 109; if (lo < 0) lo = 0;
    int hi = (k1 < 256) ? k1 : 256;
    // invariant: ok(lo) true. find max i in [lo,hi] with A[i-1] <= Bv(k1-i)
    #pragma unroll
    for (int it7 = 0; it7 < 7; ++it7) {
      if (lo < hi) {
        int mid = (lo + hi + 1) >> 1;            // >= 1
        unsigned av = __builtin_bit_cast(unsigned, base[mid - 1]);
        int j = k1 - mid;                         // >= 0
        unsigned bv = (j <= 108) ? __builtin_bit_cast(unsigned, base[256 + j]) : 0xFFFFFFFFu;
        bool ok = av <= bv;
        lo = ok ? mid : lo;
        hi = ok ? hi : mid - 1;
      }
    }
    unsigned aL = (lo >= 1) ? __builtin_bit_cast(unsigned, base[lo - 1]) : 0u;
    int jm = k1 - lo - 1;                         // <= 108 by lo >= max(0, k1-109)
    unsigned bL = (jm >= 0) ? __builtin_bit_cast(unsigned, base[256 + jm]) : 0u;
    unsigned ansu = aL > bL ? aL : bL;
    float ans = unmapkey(ansu);
    stats[(tz == 0 ? sb0 : sb1) + 1 + q] = ans;
  } else if (lane == 10) {
    stats[sb0 + 0] = sx;
  } else if (lane == 11) {
    stats[sb1 + 0] = sy;
  }
}

// Kernel 2: Theil-Sen median of 45 pairwise slopes over 10 years, per (col,stat).
__global__ __launch_bounds__(256) void k_trend(const float* __restrict__ stats,
                                               float* __restrict__ trend_part)
{
  const int tid = blockIdx.x * 256 + threadIdx.x;
  const int a32 = (((threadIdx.x & 63) ^ 32) << 2);
  float contrib = 0.f;
  if (tid < K2_THREADS) {
    float med[2];
    #pragma unroll 1
    for (int tz = 0; tz < 2; ++tz) {
      float xv[10];
      #pragma unroll
      for (int y = 0; y < NYEARS; ++y)
        xv[y] = stats[(size_t)tz * (NYEARS * NCOL * STATS_N) + (size_t)y * (NCOL * STATS_N) + tid];
      float d[45];
      int c = 0;
      #pragma unroll
      for (int i = 0; i < 10; ++i) {
        #pragma unroll
        for (int j = i + 1; j < 10; ++j) {
          d[c] = (xv[j] - xv[i]) / (float)(j - i);
          ++c;
        }
      }
      // stable rank-count selection of sorted[22] (lower-middle of 45)
      float m = 0.f;
      #pragma unroll
      for (int i = 0; i < 45; ++i) {
        int rank = 0;
        #pragma unroll
        for (int j = 0; j < 45; ++j) {
          if (j != i) {
            bool lt = (d[j] < d[i]) || ((d[j] == d[i]) && (j < i));
            rank += lt ? 1 : 0;
          }
        }
        m = (rank == 22) ? d[i] : m;
      }
      med[tz] = m;
    }
    float dd = med[1] - med[0];
    contrib = dd * dd;
  }
  float s = wsum64(contrib, a32);
  __shared__ float red[4];
  if ((threadIdx.x & 63) == 0) red[threadIdx.x >> 6] = s;
  __syncthreads();
  if (threadIdx.x == 0) trend_part[blockIdx.x] = red[0] + red[1] + red[2] + red[3];
}

// Kernel 3: deterministic final combine (single block, 1024 threads).
__global__ __launch_bounds__(1024) void k_final(const float* __restrict__ se_part,
                                                const float* __restrict__ trend_part,
                                                float* __restrict__ out)
{
  const int tid = threadIdx.x;
  const int lane = tid & 63;
  const int wid = tid >> 6;
  const int a32 = ((lane ^ 32) << 2);
  float acc[5] = {0.f, 0.f, 0.f, 0.f, 0.f};
  for (int i = tid; i < SE_BLOCKS; i += 1024) {
    #pragma unroll
    for (int v = 0; v < 5; ++v) acc[v] += se_part[i * 5 + v];
  }
  float tr = 0.f;
  for (int i = tid; i < K2_BLOCKS; i += 1024) tr += trend_part[i];

  __shared__ float red[6][16];
  #pragma unroll
  for (int q = 0; q < 6; ++q) {
    float s = wsum64(q < 5 ? acc[q] : tr, a32);
    if (lane == 0) red[q][wid] = s;
  }
  __syncthreads();
  if (tid == 0) {
    float loss = 0.f;
    const float inv = 1.f / (float)((double)NT * (double)NG);
    #pragma unroll
    for (int q = 0; q < 5; ++q) {
      float s = 0.f;
      #pragma unroll
      for (int w = 0; w < 16; ++w) s += red[q][w];
      loss += sqrtf(s * inv);
    }
    float s5 = 0.f;
    #pragma unroll
    for (int w = 0; w < 16; ++w) s5 += red[5][w];
    loss += s5 / (float)NG;
    out[0] = loss;
  }
}

extern "C" void kernel_launch(void* const* d_in, const int* in_sizes, int n_in,
                              void* d_out, int out_size, void* d_ws, size_t ws_size,
                              hipStream_t stream)
{
  const float* outp = (const float*)d_in[0];  // "output" [3650,2000,5] f32
  const float* targ = (const float*)d_in[1];  // "target" [3650,2000,5] f32
  float* out = (float*)d_out;                 // scalar f32 loss

  // ws layout (floats): stats[2*10*10000*6] | se_part[6250*5] | trend_part[235]
  float* stats = (float*)d_ws;
  float* se_part = stats + STATS_FLOATS;
  float* trend_part = se_part + SE_BLOCKS * 5;

  k_stats<<<SE_BLOCKS, 1024, 0, stream>>>(outp, targ, stats, se_part);
  k_trend<<<K2_BLOCKS, 256, 0, stream>>>(stats, trend_part);
  k_final<<<1, 1024, 0, stream>>>(se_part, trend_part, out);
}